// Round 12
// baseline (486.276 us; speedup 1.0000x reference)
//
#include <hip/hip_runtime.h>
#include <hip/hip_bf16.h>

namespace {
constexpr int NODES = 100000;
constexpr int EMBD  = 128;
constexpr int BATCH = 1024;
constexpr int NBLK  = 256;    // exactly 1 block/CU, zero residency imbalance
constexpr int NWIDE = 53;     // 53 strips of 416 cols + 203 of 384 = 100000
}

typedef __attribute__((ext_vector_type(8))) short bf16x8_t;
typedef __attribute__((ext_vector_type(4))) float f32x4_t;

__device__ __forceinline__ short f2bf(float f) {
    __hip_bfloat16 h = __float2bfloat16(f);
    short s; __builtin_memcpy(&s, &h, 2); return s;
}

// strips are multiples of 32 cols -> every block's n0 is 128B-line-aligned
__device__ __forceinline__ int strip_start(int bid) {
    return 384 * bid + 32 * ((bid * NWIDE) >> 8);   // /256
}

// combined[b][k] = emb[subj[b]][k] * rels[rel[b]][k], bf16 (A matrix, 256 KB)
__global__ void combine_kernel(const int* __restrict__ subj,
                               const int* __restrict__ rel,
                               const float* __restrict__ emb,
                               const float* __restrict__ rels,
                               short* __restrict__ out) {
    const int b = blockIdx.x;
    const int t = threadIdx.x;
    const float v = emb[(size_t)subj[b] * EMBD + t] * rels[rel[b] * EMBD + t];
    out[b * EMBD + t] = f2bf(v);
}

// One block: W-col strip (W in {384,416}, line-aligned) x all 1024 rows.
// 12 waves; wave w sweeps 16-row tiles t = w, w+12, ... (64 tiles total).
// Per row each block writes W*4 = 1536/1664 B sequential (12-13 full lines)
// -> DRAM page locality. B staged once in LDS (96/104 KB), XOR-swizzled.
template <int W>
__device__ __forceinline__ void block_body(const short* __restrict__ A,
                                           const float* __restrict__ B,
                                           float* __restrict__ C,
                                           short* Bs, int n0, int tid) {
    constexpr int NI = W / 16;            // 24 or 26
    constexpr int ELEMS = W * EMBD;

    // ---- stage B strip with 768 threads, 8 elems/thread/chunk
#pragma unroll
    for (int c = 0; c < (ELEMS + 6143) / 6144; ++c) {
        const int e = (c * 768 + tid) * 8;
        if (e < ELEMS) {
            const int rr = e >> 7;
            const int k  = e & 127;
            const float* p = B + (size_t)(n0 + rr) * EMBD + k;
            f32x4_t lo = *reinterpret_cast<const f32x4_t*>(p);
            f32x4_t hi = *reinterpret_cast<const f32x4_t*>(p + 4);
            bf16x8_t v;
#pragma unroll
            for (int j = 0; j < 4; ++j) { v[j] = f2bf(lo[j]); v[4 + j] = f2bf(hi[j]); }
            const int byteaddr = rr * 256 + ((k * 2) ^ ((rr & 7) << 4));
            *reinterpret_cast<bf16x8_t*>(reinterpret_cast<char*>(Bs) + byteaddr) = v;
        }
    }
    __syncthreads();

    const int w  = tid >> 6;              // 0..11
    const int l  = tid & 63;
    const int fr = l & 15;
    const int fq = l >> 4;
    const int swz = (fr & 7) << 4;
    const char* BsBase = reinterpret_cast<const char*>(Bs) + fr * 256;

    for (int t = w; t < 64; t += 12) {    // this wave's 16-row tiles
        const int m0 = t * 16;

        bf16x8_t a[4];
        {
            const short* qp = A + (m0 + fr) * EMBD + fq * 8;
#pragma unroll
            for (int kk = 0; kk < 4; ++kk)
                a[kk] = *reinterpret_cast<const bf16x8_t*>(qp + kk * 32);
        }

        f32x4_t acc[NI] = {};
#pragma unroll
        for (int kk = 0; kk < 4; ++kk) {
#pragma unroll
            for (int base = 0; base < NI; base += 5) {
                bf16x8_t bfr[5];
#pragma unroll
                for (int j = 0; j < 5; ++j)
                    if (base + j < NI) {
                        const int byteoff = (base + j) * 4096 +
                                            ((kk * 64 + fq * 16) ^ swz);
                        bfr[j] = *reinterpret_cast<const bf16x8_t*>(BsBase + byteoff);
                    }
#pragma unroll
                for (int j = 0; j < 5; ++j)
                    if (base + j < NI)
                        acc[base + j] = __builtin_amdgcn_mfma_f32_16x16x32_bf16(
                            bfr[j], a[kk], acc[base + j], 0, 0, 0);
            }
        }

        // D: col(fr)=batch row, row(fq*4+reg)=node -> f32x4 along N
        const size_t rowoff = (size_t)(m0 + fr) * NODES;
#pragma unroll
        for (int ni = 0; ni < NI; ++ni)
            *reinterpret_cast<f32x4_t*>(C + rowoff + n0 + ni * 16 + fq * 4) =
                acc[ni];
    }
}

// Grid = 256 x 768 threads: 1 block/CU, 12 waves/CU uniform.
__global__ __launch_bounds__(768, 3) void distmult_kernel(
        const short* __restrict__ A,
        const float* __restrict__ B,
        float* __restrict__ C) {
    extern __shared__ short Bs[];          // up to 416*128 bf16 = 104 KB
    const int bid = (int)blockIdx.x;
    const int n0  = strip_start(bid);
    const int wdt = strip_start(bid + 1) - n0;   // 384 or 416, block-uniform
    const int tid = (int)threadIdx.x;
    if (wdt == 416) block_body<416>(A, B, C, Bs, n0, tid);
    else            block_body<384>(A, B, C, Bs, n0, tid);
}

extern "C" void kernel_launch(void* const* d_in, const int* in_sizes, int n_in,
                              void* d_out, int out_size, void* d_ws, size_t ws_size,
                              hipStream_t stream) {
    const int*   subj = (const int*)d_in[0];
    const int*   rel  = (const int*)d_in[1];
    const float* emb  = (const float*)d_in[2];
    const float* rels = (const float*)d_in[3];
    float* out = (float*)d_out;
    short* combined = (short*)d_ws;   // 256 KB

    combine_kernel<<<BATCH, EMBD, 0, stream>>>(subj, rel, emb, rels, combined);
    distmult_kernel<<<NBLK, 768, 416 * EMBD * sizeof(short), stream>>>(
        combined, emb, out);
}

// Round 13
// 224.660 us; speedup vs baseline: 2.1645x; 2.1645x over previous
//
#include <hip/hip_runtime.h>
#include <hip/hip_bf16.h>

namespace {
constexpr int NODES = 100000;
constexpr int EMBD  = 128;
constexpr int BATCH = 1024;
constexpr int NBLK  = 768;    // exactly 3 blocks/CU, zero residency imbalance
constexpr int NWIDE = 53;     // 53 strips of 160 cols + 715 of 128 = 100000
constexpr int NPASS = 8;      // 1024 rows / (4 waves * 32 rows)
}

typedef __attribute__((ext_vector_type(8))) short bf16x8_t;
typedef __attribute__((ext_vector_type(4))) float f32x4_t;

__device__ __forceinline__ short f2bf(float f) {
    __hip_bfloat16 h = __float2bfloat16(f);
    short s; __builtin_memcpy(&s, &h, 2); return s;
}

// combined[b][k] = emb[subj[b]][k] * rels[rel[b]][k], bf16 (A matrix, 256 KB)
__global__ void combine_kernel(const int* __restrict__ subj,
                               const int* __restrict__ rel,
                               const float* __restrict__ emb,
                               const float* __restrict__ rels,
                               short* __restrict__ out) {
    const int b = blockIdx.x;
    const int t = threadIdx.x;
    const float v = emb[(size_t)subj[b] * EMBD + t] * rels[rel[b] * EMBD + t];
    out[b * EMBD + t] = f2bf(v);
}

// One block: W-col strip (W=160 or 128, both 32-col = 128B line multiples)
// x all 1024 batch rows. EXACT r5 body, parameterized by NI = W/16.
// 4 waves; wave w, pass p -> rows p*128 + w*32 .. +32 (2 mi-tiles of 16).
// B strip staged once in 40KB LDS (fp32 read coalesced, cvt bf16, XOR
// swizzle byte^=(row&7)<<4 -> conflict-free ds_read_b128); one barrier,
// then barrier-free 8-pass sweep. A (256KB) is L2-resident, read once/block.
// Swapped-operand MFMA: D col(lane&15)=batch row, D row(fq*4+reg)=node
//   -> f32x4 stores along N; per row each block writes W*4 B contiguous.
template <int NI>
__device__ __forceinline__ void block_body(const short* __restrict__ A,
                                           const float* __restrict__ B,
                                           float* __restrict__ C,
                                           short* Bs, int n0, int tid) {
    // ---- stage B strip: NI*16*128 bf16, NI chunks of 8 elems/thread
#pragma unroll
    for (int c = 0; c < NI; ++c) {
        const int e = (c * 256 + tid) * 8;
        const int rr = e >> 7;
        const int k  = e & 127;
        const float* p = B + (size_t)(n0 + rr) * EMBD + k;
        f32x4_t lo = *reinterpret_cast<const f32x4_t*>(p);
        f32x4_t hi = *reinterpret_cast<const f32x4_t*>(p + 4);
        bf16x8_t v;
#pragma unroll
        for (int j = 0; j < 4; ++j) { v[j] = f2bf(lo[j]); v[4 + j] = f2bf(hi[j]); }
        const int byteaddr = rr * 256 + ((k * 2) ^ ((rr & 7) << 4));
        *reinterpret_cast<bf16x8_t*>(reinterpret_cast<char*>(Bs) + byteaddr) = v;
    }
    __syncthreads();

    const int w  = tid >> 6;
    const int l  = tid & 63;
    const int fr = l & 15;
    const int fq = l >> 4;
    const int swz = (fr & 7) << 4;
    const char* BsBase = reinterpret_cast<const char*>(Bs) + fr * 256;

#pragma unroll
    for (int p = 0; p < NPASS; ++p) {
        const int m0 = p * 128 + w * 32;
        bf16x8_t a[2][4];
#pragma unroll
        for (int mi = 0; mi < 2; ++mi) {
            const short* qp = A + (m0 + mi * 16 + fr) * EMBD + fq * 8;
#pragma unroll
            for (int kk = 0; kk < 4; ++kk)
                a[mi][kk] = *reinterpret_cast<const bf16x8_t*>(qp + kk * 32);
        }

        f32x4_t acc[2][NI] = {};
#pragma unroll
        for (int kk = 0; kk < 4; ++kk) {
#pragma unroll
            for (int base = 0; base < NI; base += 5) {
                bf16x8_t bfr[5];
#pragma unroll
                for (int j = 0; j < 5; ++j)
                    if (base + j < NI) {
                        const int byteoff = (base + j) * 4096 +
                                            ((kk * 64 + fq * 16) ^ swz);
                        bfr[j] = *reinterpret_cast<const bf16x8_t*>(BsBase + byteoff);
                    }
#pragma unroll
                for (int mi = 0; mi < 2; ++mi)
#pragma unroll
                    for (int j = 0; j < 5; ++j)
                        if (base + j < NI)
                            acc[mi][base + j] = __builtin_amdgcn_mfma_f32_16x16x32_bf16(
                                bfr[j], a[mi][kk], acc[mi][base + j], 0, 0, 0);
            }
        }

#pragma unroll
        for (int mi = 0; mi < 2; ++mi) {
            const size_t rowoff = (size_t)(m0 + mi * 16 + fr) * NODES;
#pragma unroll
            for (int ni = 0; ni < NI; ++ni)
                *reinterpret_cast<f32x4_t*>(C + rowoff + n0 + ni * 16 + fq * 4) =
                    acc[mi][ni];
        }
    }
}

// Grid = 768 blocks (exactly 3/CU): bid<53 -> 160-col strip, else 128-col.
// n0: bid<53 ? 160*bid : 128*bid + 1696   (53*160 + (bid-53)*128)
__global__ __launch_bounds__(256, 3) void distmult_kernel(
        const short* __restrict__ A,
        const float* __restrict__ B,
        float* __restrict__ C) {
    __shared__ short Bs[160 * EMBD];       // 40 KB (max strip)
    const int bid = (int)blockIdx.x;
    const int tid = (int)threadIdx.x;
    if (bid < NWIDE) {
        block_body<10>(A, B, C, Bs, 160 * bid, tid);
    } else {
        block_body<8>(A, B, C, Bs, 128 * bid + 1696, tid);
    }
}

extern "C" void kernel_launch(void* const* d_in, const int* in_sizes, int n_in,
                              void* d_out, int out_size, void* d_ws, size_t ws_size,
                              hipStream_t stream) {
    const int*   subj = (const int*)d_in[0];
    const int*   rel  = (const int*)d_in[1];
    const float* emb  = (const float*)d_in[2];
    const float* rels = (const float*)d_in[3];
    float* out = (float*)d_out;
    short* combined = (short*)d_ws;   // 256 KB

    combine_kernel<<<BATCH, EMBD, 0, stream>>>(subj, rel, emb, rels, combined);
    distmult_kernel<<<NBLK, 256, 0, stream>>>(combined, emb, out);
}